// Round 6
// baseline (83.378 us; speedup 1.0000x reference)
//
#include <hip/hip_runtime.h>

// SeriesDecomp: x (32, 512, 2048) f32. Moving average K=2049, replicate pad p=1024.
// d_out = [x_s (N floats) | x_t (N floats)], x_t = movavg, x_s = x - x_t.
//
// Closed form via row prefix sums (pfx inclusive, epfx exclusive):
//   i <  1024: wsum = (1024-i)*x[0] + pfx[i+1024]
//   i >= 1024: wsum = (i-1023)*x[L-1] + total - epfx[i-1024]   (epfx[0]=0)
//
// Contiguous ownership (thread t owns [8t,8t+8)), single LDS array w of
// prefix values (lower half exclusive, upper half inclusive), and an
// XOR swizzle on f4-chunk index  c' = c ^ ((c>>3)&7)  so that BOTH the
// publish (c=2t,2t+1) and the consume (c=2t±256) ds_*_b128 accesses put
// exactly 8 lanes on each 4-bank quad — conflict-free. x stays in regs;
// 2 global dwordx4 loads + 4 dwordx4 stores per thread (regular, cached —
// NT stores regressed 40% in R3).

#define ROWLEN 2048

typedef float f4 __attribute__((ext_vector_type(4)));

__device__ __forceinline__ int swz(int c) { return c ^ ((c >> 3) & 7); }

__global__ __launch_bounds__(256) void series_decomp_kernel(
    const float* __restrict__ x,
    float* __restrict__ xs_out,
    float* __restrict__ xt_out)
{
    __shared__ f4 w4[ROWLEN / 4];   // swizzled prefix chunks
    __shared__ float wsum4[4];
    __shared__ float edge[2];       // [0]=x[0], [1]=x[2047]

    const int t = threadIdx.x;
    const size_t rowoff = (size_t)blockIdx.x * ROWLEN;

    // Load 8 contiguous floats (2x dwordx4).
    const f4* xin = reinterpret_cast<const f4*>(x + rowoff);
    const f4 a = xin[2 * t];
    const f4 b = xin[2 * t + 1];

    if (t == 0)   edge[0] = a.x;
    if (t == 255) edge[1] = b.w;

    // In-register inclusive scan of the 8 elements.
    const float s0 = a.x;
    const float s1 = s0 + a.y;
    const float s2 = s1 + a.z;
    const float s3 = s2 + a.w;
    const float s4 = s3 + b.x;
    const float s5 = s4 + b.y;
    const float s6 = s5 + b.z;
    const float s7 = s6 + b.w;
    const float tot = s7;

    // Wave (64-lane) inclusive shuffle scan of per-thread totals.
    const int lane = t & 63;
    float sc = tot;
    #pragma unroll
    for (int d = 1; d < 64; d <<= 1) {
        const float o = __shfl_up(sc, d, 64);
        if (lane >= d) sc += o;
    }
    const int wid = t >> 6;
    if (lane == 63) wsum4[wid] = sc;
    __syncthreads();

    // Exclusive prefix preceding this thread's first element.
    float base = sc - tot;
    #pragma unroll
    for (int ww = 0; ww < 3; ++ww)
        if (ww < wid) base += wsum4[ww];

    // Publish: lower half EXCLUSIVE prefix, upper half INCLUSIVE. Swizzled.
    f4 w0, w1;
    if (t < 128) {
        w0 = (f4){base,      base + s0, base + s1, base + s2};
        w1 = (f4){base + s3, base + s4, base + s5, base + s6};
    } else {
        w0 = (f4){base + s0, base + s1, base + s2, base + s3};
        w1 = (f4){base + s4, base + s5, base + s6, base + s7};
    }
    w4[swz(2 * t)]     = w0;
    w4[swz(2 * t + 1)] = w1;
    __syncthreads();

    const float x0    = edge[0];
    const float xl    = edge[1];
    const float total = w4[swz(511)].w;   // pfx[2047] (upper half inclusive)
    const float invK  = 1.0f / 2049.0f;

    // Fetch partner prefix block (two conflict-free ds_read_b128).
    f4 p0, p1;
    if (t < 128) {
        p0 = w4[swz(2 * t + 256)];   // pfx[8t+1024 .. +3]
        p1 = w4[swz(2 * t + 257)];   // pfx[8t+1028 .. +3]
    } else {
        p0 = w4[swz(2 * t - 256)];   // epfx[8t-1024 .. +3]
        p1 = w4[swz(2 * t - 255)];
    }

    const int i0 = 8 * t;
    f4 xt0, xt1;
    if (t < 128) {
        xt0.x = ((float)(1024 - (i0 + 0)) * x0 + p0.x) * invK;
        xt0.y = ((float)(1024 - (i0 + 1)) * x0 + p0.y) * invK;
        xt0.z = ((float)(1024 - (i0 + 2)) * x0 + p0.z) * invK;
        xt0.w = ((float)(1024 - (i0 + 3)) * x0 + p0.w) * invK;
        xt1.x = ((float)(1024 - (i0 + 4)) * x0 + p1.x) * invK;
        xt1.y = ((float)(1024 - (i0 + 5)) * x0 + p1.y) * invK;
        xt1.z = ((float)(1024 - (i0 + 6)) * x0 + p1.z) * invK;
        xt1.w = ((float)(1024 - (i0 + 7)) * x0 + p1.w) * invK;
    } else {
        xt0.x = ((float)((i0 + 0) - 1023) * xl + (total - p0.x)) * invK;
        xt0.y = ((float)((i0 + 1) - 1023) * xl + (total - p0.y)) * invK;
        xt0.z = ((float)((i0 + 2) - 1023) * xl + (total - p0.z)) * invK;
        xt0.w = ((float)((i0 + 3) - 1023) * xl + (total - p0.w)) * invK;
        xt1.x = ((float)((i0 + 4) - 1023) * xl + (total - p1.x)) * invK;
        xt1.y = ((float)((i0 + 5) - 1023) * xl + (total - p1.y)) * invK;
        xt1.z = ((float)((i0 + 6) - 1023) * xl + (total - p1.z)) * invK;
        xt1.w = ((float)((i0 + 7) - 1023) * xl + (total - p1.w)) * invK;
    }

    const f4 xs0 = a - xt0;
    const f4 xs1 = b - xt1;

    f4* xs4 = reinterpret_cast<f4*>(xs_out + rowoff);
    f4* xt4 = reinterpret_cast<f4*>(xt_out + rowoff);
    xs4[2 * t]     = xs0;
    xs4[2 * t + 1] = xs1;
    xt4[2 * t]     = xt0;
    xt4[2 * t + 1] = xt1;
}

extern "C" void kernel_launch(void* const* d_in, const int* in_sizes, int n_in,
                              void* d_out, int out_size, void* d_ws, size_t ws_size,
                              hipStream_t stream) {
    const float* x = (const float*)d_in[0];
    const int n = in_sizes[0];              // 32*512*2048
    const int rows = n / ROWLEN;            // 16384
    float* xs = (float*)d_out;              // output 0: seasonal
    float* xt = (float*)d_out + (size_t)n;  // output 1: trend
    series_decomp_kernel<<<rows, 256, 0, stream>>>(x, xs, xt);
}